// Round 1
// baseline (381.359 us; speedup 1.0000x reference)
//
#include <hip/hip_runtime.h>
#include <hip/hip_bf16.h>
#include <cstdint>
#include <cstddef>

#define SEQ    2048
#define DMODEL 1024
#define DEXP   2048
#define NHEADS 16
#define DHEAD  128

typedef __bf16 bf16x8 __attribute__((ext_vector_type(8)));
typedef float  f32x4  __attribute__((ext_vector_type(4)));

__device__ __forceinline__ unsigned short f2bf(float f) {
  unsigned int u = __builtin_bit_cast(unsigned int, f);
  u = u + 0x7FFFu + ((u >> 16) & 1u);   // round-to-nearest-even
  return (unsigned short)(u >> 16);
}
__device__ __forceinline__ float bf2f(unsigned short h) {
  unsigned int u = ((unsigned int)h) << 16;
  return __builtin_bit_cast(float, u);
}

// ---------------- LayerNorm (one row of 1024 per block, 256 threads) ----------------
__global__ __launch_bounds__(256) void ln_kernel(const float* __restrict__ in,
    const float* __restrict__ gw, const float* __restrict__ gb,
    unsigned short* __restrict__ out_bf, float* __restrict__ out_f) {
  int row = blockIdx.x, t = threadIdx.x;
  const float4* ip = reinterpret_cast<const float4*>(in + (size_t)row * DMODEL);
  float4 v = ip[t];
  float s  = v.x + v.y + v.z + v.w;
  float ss = v.x*v.x + v.y*v.y + v.z*v.z + v.w*v.w;
  #pragma unroll
  for (int m = 1; m < 64; m <<= 1) { s += __shfl_xor(s, m, 64); ss += __shfl_xor(ss, m, 64); }
  __shared__ float sh[8];
  if ((t & 63) == 0) { sh[t >> 6] = s; sh[4 + (t >> 6)] = ss; }
  __syncthreads();
  s  = sh[0] + sh[1] + sh[2] + sh[3];
  ss = sh[4] + sh[5] + sh[6] + sh[7];
  float mu  = s * (1.0f / DMODEL);
  float var = ss * (1.0f / DMODEL) - mu * mu;
  float rs  = rsqrtf(var + 1e-5f);
  float4 w4 = reinterpret_cast<const float4*>(gw)[t];
  float4 b4 = reinterpret_cast<const float4*>(gb)[t];
  float o0 = (v.x - mu) * rs * w4.x + b4.x;
  float o1 = (v.y - mu) * rs * w4.y + b4.y;
  float o2 = (v.z - mu) * rs * w4.z + b4.z;
  float o3 = (v.w - mu) * rs * w4.w + b4.w;
  if (out_bf) {
    unsigned short* op = out_bf + (size_t)row * DMODEL + t * 4;
    op[0] = f2bf(o0); op[1] = f2bf(o1); op[2] = f2bf(o2); op[3] = f2bf(o3);
  } else {
    float4 o4; o4.x = o0; o4.y = o1; o4.z = o2; o4.w = o3;
    reinterpret_cast<float4*>(out_f + (size_t)row * DMODEL)[t] = o4;
  }
}

// ---------------- f32 -> bf16 cast, 4 elems/thread ----------------
__global__ void castbf4(const float* __restrict__ in, unsigned short* __restrict__ out, int n4) {
  int i = blockIdx.x * 256 + threadIdx.x;
  if (i >= n4) return;
  float4 v = reinterpret_cast<const float4*>(in)[i];
  ushort4 o;
  o.x = f2bf(v.x); o.y = f2bf(v.y); o.z = f2bf(v.z); o.w = f2bf(v.w);
  reinterpret_cast<ushort4*>(out)[i] = o;
}

// ---------------- GEMM  C[M,N] = A[M,K] * B[N,K]^T  (both bf16 row-major, K contiguous) ----
// Wave tile 64x64 (4x4 frags of 16x16x32).  WM x WN waves per block.
// EPI 0: proj epilogue (bias + split into q(scaled)/k/vT/p bf16 buffers)
// EPI 1: plain f32 store
template<int WM, int WN, int EPI>
__global__ __launch_bounds__(WM * WN * 64) void gemm_bt(
    const unsigned short* __restrict__ A, const unsigned short* __restrict__ B,
    int M, int N, int K,
    const float* __restrict__ b_in, const float* __restrict__ log_scale,
    unsigned short* __restrict__ outq, unsigned short* __restrict__ outk,
    unsigned short* __restrict__ outvt, unsigned short* __restrict__ outp,
    float* __restrict__ outf) {
  int nbn = N / (WN * 64);
  int bm = blockIdx.x / nbn, bn = blockIdx.x % nbn;
  int tid = threadIdx.x;
  int wid = tid >> 6, l = tid & 63;
  int wr = wid / WN, wc = wid % WN;
  int row0 = bm * WM * 64 + wr * 64;
  int col0 = bn * WN * 64 + wc * 64;
  int c16 = l & 15, g = l >> 4;

  f32x4 acc[4][4];
  f32x4 z = {0.f, 0.f, 0.f, 0.f};
  #pragma unroll
  for (int i = 0; i < 4; ++i)
    #pragma unroll
    for (int j = 0; j < 4; ++j) acc[i][j] = z;

  const unsigned short* Ab = A + (size_t)(row0 + c16) * K + g * 8;
  const unsigned short* Bb = B + (size_t)(col0 + c16) * K + g * 8;

  for (int k0 = 0; k0 < K; k0 += 32) {
    bf16x8 a[4], b[4];
    #pragma unroll
    for (int i = 0; i < 4; ++i)
      a[i] = *reinterpret_cast<const bf16x8*>(Ab + (size_t)i * 16 * K + k0);
    #pragma unroll
    for (int i = 0; i < 4; ++i)
      b[i] = *reinterpret_cast<const bf16x8*>(Bb + (size_t)i * 16 * K + k0);
    #pragma unroll
    for (int i = 0; i < 4; ++i)
      #pragma unroll
      for (int j = 0; j < 4; ++j)
        acc[i][j] = __builtin_amdgcn_mfma_f32_16x16x32_bf16(a[i], b[j], acc[i][j], 0, 0, 0);
  }

  #pragma unroll
  for (int i = 0; i < 4; ++i) {
    #pragma unroll
    for (int j = 0; j < 4; ++j) {
      #pragma unroll
      for (int r = 0; r < 4; ++r) {
        int gi = row0 + i * 16 + g * 4 + r;      // C/D row = (lane>>4)*4 + reg
        int n  = col0 + j * 16 + c16;            // C/D col = lane&15
        float val = acc[i][j][r];
        if constexpr (EPI == 0) {
          val += b_in[n];
          int sec = n >> 11, nn = n & 2047, hh = nn >> 7;
          if (sec == 0) {
            float qs = __expf(-2.f * log_scale[hh]) * 0.088388347648318447f; // 1/(s^2*sqrt(128))
            outq[(size_t)gi * DEXP + nn] = f2bf(val * qs);
          } else if (sec == 1) {
            outk[(size_t)gi * DEXP + nn] = f2bf(val);
          } else if (sec == 2) {
            outvt[(size_t)nn * SEQ + gi] = f2bf(val);   // V stored transposed: vt[h*128+d][i]
          } else {
            outp[(size_t)gi * DEXP + nn] = f2bf(val);
          }
        } else {
          outf[(size_t)gi * N + n] = val;
        }
      }
    }
  }
}

// ---------------- y head: dot(xn_row, W_in[8192+h]) + bias -> sigmoid -> sig_y[h][i] ------
__global__ __launch_bounds__(256) void yproj(const unsigned short* __restrict__ xn,
    const unsigned short* __restrict__ winbf, const float* __restrict__ b_in,
    float* __restrict__ sig_y) {
  int i = blockIdx.x;
  int t = threadIdx.x, wv = t >> 6, l = t & 63;
  const unsigned short* xr = xn + (size_t)i * DMODEL;
  for (int h = wv; h < NHEADS; h += 4) {
    const unsigned short* wr = winbf + (size_t)(4 * DEXP + h) * DMODEL;
    float s = 0.f;
    #pragma unroll
    for (int e = 0; e < 16; ++e) {
      int idx = l + 64 * e;
      s += bf2f(xr[idx]) * bf2f(wr[idx]);
    }
    #pragma unroll
    for (int m = 1; m < 64; m <<= 1) s += __shfl_xor(s, m, 64);
    if (l == 0) {
      float yv = s + b_in[4 * DEXP + h];
      sig_y[h * SEQ + i] = 1.f / (1.f + __expf(-yv));
    }
  }
}

// ---------------- inclusive scan of sig_y per head -> pos[h][i] ----------------
__global__ __launch_bounds__(256) void scan_kernel(const float* __restrict__ sig_y,
                                                   float* __restrict__ pos) {
  int h = blockIdx.x, t = threadIdx.x;
  const float* in = sig_y + (size_t)h * SEQ;
  float v[8], s = 0.f;
  #pragma unroll
  for (int e = 0; e < 8; ++e) { v[e] = in[t * 8 + e]; s += v[e]; }
  __shared__ float sh[256];
  sh[t] = s;
  __syncthreads();
  for (int off = 1; off < 256; off <<= 1) {
    float add = (t >= off) ? sh[t - off] : 0.f;
    __syncthreads();
    sh[t] += add;
    __syncthreads();
  }
  float run = sh[t] - s;   // exclusive prefix of thread sums
  float* op = pos + (size_t)h * SEQ;
  #pragma unroll
  for (int e = 0; e < 8; ++e) { run += v[e]; op[t * 8 + e] = run; }
}

// ---------------- smear: k <- (1-s)k_t + s k_{t-1} ----------------
__global__ void smear_kernel(const unsigned short* __restrict__ projk,
    const float* __restrict__ smearf, unsigned short* __restrict__ ksm) {
  int idx = blockIdx.x * 256 + threadIdx.x;
  if (idx >= SEQ * DEXP) return;
  int i = idx >> 11, nn = idx & 2047, h = nn >> 7;
  float sf = 1.f / (1.f + __expf(-smearf[h]));
  float kc = bf2f(projk[idx]);
  float kp = (i > 0) ? bf2f(projk[idx - DEXP]) : 0.f;
  ksm[idx] = f2bf((1.f - sf) * kc + sf * kp);
}

// ---------------- flash attention: 1 wave per (head, 16-row q tile) ----------------
__global__ __launch_bounds__(64) void attn_kernel(
    const unsigned short* __restrict__ q, const unsigned short* __restrict__ ksm,
    const unsigned short* __restrict__ vt, const unsigned short* __restrict__ projp,
    const float* __restrict__ pos, unsigned short* __restrict__ ap) {
  int bid = blockIdx.x;
  int h = bid & (NHEADS - 1);
  int qt = bid >> 4;
  int l = threadIdx.x;
  int c16 = l & 15, g = l >> 4;

  // Q A-fragments (row = lane%16, k = (lane/16)*8 + j), q pre-scaled by 1/(s^2 sqrt(d))
  bf16x8 qf[4];
  {
    const unsigned short* qb = q + (size_t)(qt * 16 + c16) * DEXP + h * DHEAD + g * 8;
    #pragma unroll
    for (int f = 0; f < 4; ++f) qf[f] = *reinterpret_cast<const bf16x8*>(qb + f * 32);
  }
  float pos_i[4];
  #pragma unroll
  for (int r = 0; r < 4; ++r) pos_i[r] = pos[h * SEQ + qt * 16 + g * 4 + r];

  float m_run[4], l_run[4];
  #pragma unroll
  for (int r = 0; r < 4; ++r) { m_run[r] = -1e30f; l_run[r] = 0.f; }
  f32x4 oacc[8];
  f32x4 z = {0.f, 0.f, 0.f, 0.f};
  #pragma unroll
  for (int nb = 0; nb < 8; ++nb) oacc[nb] = z;

  __shared__ unsigned short P_lds[16 * 36];   // stride 36 shorts = 72B (8B-aligned reads, bank-benign)

  int jt_max = (qt * 16 + 15) >> 5;
  for (int jt = 0; jt <= jt_max; ++jt) {
    int j0 = jt * 32;
    // S tile 16x32 = two 16x16 D-frags, K=128 in 4 MFMA steps
    f32x4 s0 = z, s1 = z;
    {
      const unsigned short* kb0 = ksm + (size_t)(j0 + c16) * DEXP + h * DHEAD + g * 8;
      const unsigned short* kb1 = kb0 + (size_t)16 * DEXP;
      #pragma unroll
      for (int f = 0; f < 4; ++f) {
        bf16x8 k0v = *reinterpret_cast<const bf16x8*>(kb0 + f * 32);
        bf16x8 k1v = *reinterpret_cast<const bf16x8*>(kb1 + f * 32);
        s0 = __builtin_amdgcn_mfma_f32_16x16x32_bf16(qf[f], k0v, s0, 0, 0, 0);
        s1 = __builtin_amdgcn_mfma_f32_16x16x32_bf16(qf[f], k1v, s1, 0, 0, 0);
      }
    }
    float pj0 = pos[h * SEQ + j0 + c16];
    float pj1 = pos[h * SEQ + j0 + 16 + c16];
    float v0[4], v1[4], mt[4];
    #pragma unroll
    for (int r = 0; r < 4; ++r) {
      int row = qt * 16 + g * 4 + r;
      int col0 = j0 + c16, col1 = col0 + 16;
      float a0 = s0[r] - pos_i[r] + pj0 + (col0 > row ? -1e10f : 0.f);
      float a1 = s1[r] - pos_i[r] + pj1 + (col1 > row ? -1e10f : 0.f);
      v0[r] = a0; v1[r] = a1;
      mt[r] = fmaxf(a0, a1);
    }
    #pragma unroll
    for (int r = 0; r < 4; ++r)
      #pragma unroll
      for (int m = 1; m < 16; m <<= 1)
        mt[r] = fmaxf(mt[r], __shfl_xor(mt[r], m, 64));
    float alpha[4], ps[4];
    #pragma unroll
    for (int r = 0; r < 4; ++r) {
      float mn = fmaxf(m_run[r], mt[r]);
      alpha[r] = __expf(m_run[r] - mn);
      m_run[r] = mn;
      float p0 = __expf(v0[r] - mn);
      float p1 = __expf(v1[r] - mn);
      P_lds[(g * 4 + r) * 36 + c16]      = f2bf(p0);
      P_lds[(g * 4 + r) * 36 + 16 + c16] = f2bf(p1);
      ps[r] = p0 + p1;
    }
    #pragma unroll
    for (int r = 0; r < 4; ++r) {
      #pragma unroll
      for (int m = 1; m < 16; m <<= 1) ps[r] += __shfl_xor(ps[r], m, 64);
      l_run[r] = l_run[r] * alpha[r] + ps[r];
    }
    #pragma unroll
    for (int nb = 0; nb < 8; ++nb)
      #pragma unroll
      for (int r = 0; r < 4; ++r) oacc[nb][r] *= alpha[r];
    __syncthreads();
    // P as A-fragment: lane reads P_lds[lane%16][(lane/16)*8 .. +7]
    union { unsigned long long u[2]; bf16x8 v; } pa;
    const unsigned long long* pl =
        reinterpret_cast<const unsigned long long*>(&P_lds[c16 * 36 + g * 8]);
    pa.u[0] = pl[0]; pa.u[1] = pl[1];
    #pragma unroll
    for (int nb = 0; nb < 8; ++nb) {
      const unsigned short* vb = vt + (size_t)(h * DHEAD + nb * 16 + c16) * SEQ + j0 + g * 8;
      bf16x8 vf = *reinterpret_cast<const bf16x8*>(vb);
      oacc[nb] = __builtin_amdgcn_mfma_f32_16x16x32_bf16(pa.v, vf, oacc[nb], 0, 0, 0);
    }
    __syncthreads();
  }
  // epilogue: o/l, gate with silu(p), store bf16
  #pragma unroll
  for (int nb = 0; nb < 8; ++nb) {
    #pragma unroll
    for (int r = 0; r < 4; ++r) {
      int row = qt * 16 + g * 4 + r;
      int nn = h * DHEAD + nb * 16 + c16;
      float o = oacc[nb][r] / l_run[r];
      float p = bf2f(projp[(size_t)row * DEXP + nn]);
      float si = p / (1.f + __expf(-p));
      ap[(size_t)row * DEXP + nn] = f2bf(si * o);
    }
  }
}

extern "C" void kernel_launch(void* const* d_in, const int* in_sizes, int n_in,
                              void* d_out, int out_size, void* d_ws, size_t ws_size,
                              hipStream_t stream) {
  const float* x         = (const float*)d_in[0];
  const float* W_in      = (const float*)d_in[1];
  const float* b_in      = (const float*)d_in[2];
  const float* in_ln_w   = (const float*)d_in[3];
  const float* in_ln_b   = (const float*)d_in[4];
  const float* W_out     = (const float*)d_in[5];
  const float* out_ln_w  = (const float*)d_in[6];
  const float* out_ln_b  = (const float*)d_in[7];
  const float* smearf    = (const float*)d_in[8];
  const float* log_scale = (const float*)d_in[9];
  float* out = (float*)d_out;

  char* ws = (char*)d_ws;
  size_t off = 0;
  auto alloc = [&](size_t bytes) -> void* {
    void* p = ws + off;
    off += (bytes + 255) & ~(size_t)255;
    return p;
  };
  unsigned short* xn     = (unsigned short*)alloc((size_t)SEQ * DMODEL * 2);
  unsigned short* winbf  = (unsigned short*)alloc((size_t)(4 * DEXP + NHEADS) * DMODEL * 2);
  unsigned short* woutbf = (unsigned short*)alloc((size_t)DMODEL * DEXP * 2);
  unsigned short* projq  = (unsigned short*)alloc((size_t)SEQ * DEXP * 2);
  unsigned short* projk  = (unsigned short*)alloc((size_t)SEQ * DEXP * 2);
  unsigned short* projp  = (unsigned short*)alloc((size_t)SEQ * DEXP * 2);
  unsigned short* vtb    = (unsigned short*)alloc((size_t)SEQ * DEXP * 2);
  unsigned short* ksm    = (unsigned short*)alloc((size_t)SEQ * DEXP * 2);
  unsigned short* apb    = (unsigned short*)alloc((size_t)SEQ * DEXP * 2);
  float* sig_y = (float*)alloc((size_t)NHEADS * SEQ * 4);
  float* posb  = (float*)alloc((size_t)NHEADS * SEQ * 4);
  float* outf  = (float*)alloc((size_t)SEQ * DMODEL * 4);

  int nwin4  = (4 * DEXP + NHEADS) * DMODEL / 4;
  int nwout4 = DMODEL * DEXP / 4;
  castbf4<<<(nwin4 + 255) / 256, 256, 0, stream>>>(W_in, winbf, nwin4);
  castbf4<<<(nwout4 + 255) / 256, 256, 0, stream>>>(W_out, woutbf, nwout4);
  ln_kernel<<<SEQ, 256, 0, stream>>>(x, in_ln_w, in_ln_b, xn, nullptr);
  gemm_bt<2, 2, 0><<<(SEQ / 128) * (4 * DEXP / 128), 256, 0, stream>>>(
      xn, winbf, SEQ, 4 * DEXP, DMODEL, b_in, log_scale, projq, projk, vtb, projp, nullptr);
  yproj<<<SEQ, 256, 0, stream>>>(xn, winbf, b_in, sig_y);
  scan_kernel<<<NHEADS, 256, 0, stream>>>(sig_y, posb);
  smear_kernel<<<(SEQ * DEXP + 255) / 256, 256, 0, stream>>>(projk, smearf, ksm);
  attn_kernel<<<NHEADS * (SEQ / 16), 64, 0, stream>>>(projq, ksm, vtb, projp, posb, apb);
  gemm_bt<1, 1, 1><<<(SEQ / 64) * (DMODEL / 64), 64, 0, stream>>>(
      apb, woutbf, SEQ, DMODEL, DEXP, nullptr, nullptr, nullptr, nullptr, nullptr, nullptr, outf);
  ln_kernel<<<SEQ, 256, 0, stream>>>(outf, out_ln_w, out_ln_b, nullptr, out);
}

// Round 2
// 324.049 us; speedup vs baseline: 1.1769x; 1.1769x over previous
//
#include <hip/hip_runtime.h>
#include <hip/hip_bf16.h>
#include <cstdint>
#include <cstddef>

#define SEQ    2048
#define DMODEL 1024
#define DEXP   2048
#define NHEADS 16
#define DHEAD  128

typedef __bf16 bf16x8 __attribute__((ext_vector_type(8)));
typedef float  f32x4  __attribute__((ext_vector_type(4)));

__device__ __forceinline__ unsigned short f2bf(float f) {
  unsigned int u = __builtin_bit_cast(unsigned int, f);
  u = u + 0x7FFFu + ((u >> 16) & 1u);   // round-to-nearest-even
  return (unsigned short)(u >> 16);
}
__device__ __forceinline__ float bf2f(unsigned short h) {
  unsigned int u = ((unsigned int)h) << 16;
  return __builtin_bit_cast(float, u);
}

__device__ __forceinline__ void gload_lds16(const void* g, void* l) {
  __builtin_amdgcn_global_load_lds(
      (const __attribute__((address_space(1))) unsigned int*)g,
      (__attribute__((address_space(3))) unsigned int*)l, 16, 0, 0);
}

// ---------------- LayerNorm (one row of 1024 per block, 256 threads) ----------------
__global__ __launch_bounds__(256) void ln_kernel(const float* __restrict__ in,
    const float* __restrict__ gw, const float* __restrict__ gb,
    unsigned short* __restrict__ out_bf, float* __restrict__ out_f) {
  int row = blockIdx.x, t = threadIdx.x;
  const float4* ip = reinterpret_cast<const float4*>(in + (size_t)row * DMODEL);
  float4 v = ip[t];
  float s  = v.x + v.y + v.z + v.w;
  float ss = v.x*v.x + v.y*v.y + v.z*v.z + v.w*v.w;
  #pragma unroll
  for (int m = 1; m < 64; m <<= 1) { s += __shfl_xor(s, m, 64); ss += __shfl_xor(ss, m, 64); }
  __shared__ float sh[8];
  if ((t & 63) == 0) { sh[t >> 6] = s; sh[4 + (t >> 6)] = ss; }
  __syncthreads();
  s  = sh[0] + sh[1] + sh[2] + sh[3];
  ss = sh[4] + sh[5] + sh[6] + sh[7];
  float mu  = s * (1.0f / DMODEL);
  float var = ss * (1.0f / DMODEL) - mu * mu;
  float rs  = rsqrtf(var + 1e-5f);
  float4 w4 = reinterpret_cast<const float4*>(gw)[t];
  float4 b4 = reinterpret_cast<const float4*>(gb)[t];
  float o0 = (v.x - mu) * rs * w4.x + b4.x;
  float o1 = (v.y - mu) * rs * w4.y + b4.y;
  float o2 = (v.z - mu) * rs * w4.z + b4.z;
  float o3 = (v.w - mu) * rs * w4.w + b4.w;
  if (out_bf) {
    unsigned short* op = out_bf + (size_t)row * DMODEL + t * 4;
    op[0] = f2bf(o0); op[1] = f2bf(o1); op[2] = f2bf(o2); op[3] = f2bf(o3);
  } else {
    float4 o4; o4.x = o0; o4.y = o1; o4.z = o2; o4.w = o3;
    reinterpret_cast<float4*>(out_f + (size_t)row * DMODEL)[t] = o4;
  }
}

// ---------------- f32 -> bf16 cast, 4 elems/thread ----------------
__global__ void castbf4(const float* __restrict__ in, unsigned short* __restrict__ out, int n4) {
  int i = blockIdx.x * 256 + threadIdx.x;
  if (i >= n4) return;
  float4 v = reinterpret_cast<const float4*>(in)[i];
  ushort4 o;
  o.x = f2bf(v.x); o.y = f2bf(v.y); o.z = f2bf(v.z); o.w = f2bf(v.w);
  reinterpret_cast<ushort4*>(out)[i] = o;
}

// ---------------- GEMM  C[M,N] = A[M,K] * B[N,K]^T,  LDS-staged (m97 structure) ----------
// 128x128 block tile, 4 waves (2x2 of 64x64), BK=32, global_load_lds width 16.
// EPI 0: proj epilogue (bias + split into q(scaled)/k/vT/p bf16 buffers)
// EPI 1: plain f32 store
template<int EPI>
__global__ __launch_bounds__(256) void gemm_lds(
    const unsigned short* __restrict__ A, const unsigned short* __restrict__ B,
    int M, int N, int K,
    const float* __restrict__ b_in, const float* __restrict__ log_scale,
    unsigned short* __restrict__ outq, unsigned short* __restrict__ outk,
    unsigned short* __restrict__ outvt, unsigned short* __restrict__ outp,
    float* __restrict__ outf) {
  int nbn = N / 128;
  int bm = blockIdx.x / nbn, bn = blockIdx.x % nbn;
  int tid = threadIdx.x;
  int wid = tid >> 6, l = tid & 63;
  int wr = wid >> 1, wc = wid & 1;
  int row0 = bm * 128, col0 = bn * 128;
  int c16 = l & 15, g = l >> 4;
  int srow = l >> 2;          // staging: lane -> row-within-16 group
  int skb  = (l & 3) * 8;     // staging: lane -> k-element offset (8 shorts = 16B)

  __shared__ __align__(16) unsigned short As[128 * 32];
  __shared__ __align__(16) unsigned short Bs[128 * 32];

  f32x4 acc[4][4];
  f32x4 z = {0.f, 0.f, 0.f, 0.f};
  #pragma unroll
  for (int i = 0; i < 4; ++i)
    #pragma unroll
    for (int j = 0; j < 4; ++j) acc[i][j] = z;

  for (int k0 = 0; k0 < K; k0 += 32) {
    #pragma unroll
    for (int qq = 0; qq < 2; ++qq) {
      int t = wid * 2 + qq;                 // 0..7, covers rows t*16..t*16+15
      gload_lds16(A + (size_t)(row0 + t * 16 + srow) * K + k0 + skb, As + t * 512);
      gload_lds16(B + (size_t)(col0 + t * 16 + srow) * K + k0 + skb, Bs + t * 512);
    }
    __syncthreads();   // drains vmcnt -> LDS writes visible
    bf16x8 a[4], b[4];
    #pragma unroll
    for (int i = 0; i < 4; ++i)
      a[i] = *reinterpret_cast<const bf16x8*>(As + (wr * 64 + i * 16 + c16) * 32 + g * 8);
    #pragma unroll
    for (int j = 0; j < 4; ++j)
      b[j] = *reinterpret_cast<const bf16x8*>(Bs + (wc * 64 + j * 16 + c16) * 32 + g * 8);
    #pragma unroll
    for (int i = 0; i < 4; ++i)
      #pragma unroll
      for (int j = 0; j < 4; ++j)
        acc[i][j] = __builtin_amdgcn_mfma_f32_16x16x32_bf16(a[i], b[j], acc[i][j], 0, 0, 0);
    __syncthreads();   // protect LDS from next stage
  }

  #pragma unroll
  for (int i = 0; i < 4; ++i) {
    #pragma unroll
    for (int j = 0; j < 4; ++j) {
      #pragma unroll
      for (int r = 0; r < 4; ++r) {
        int gi = row0 + wr * 64 + i * 16 + g * 4 + r;   // C/D row = (lane>>4)*4 + reg
        int n  = col0 + wc * 64 + j * 16 + c16;         // C/D col = lane&15
        float val = acc[i][j][r];
        if constexpr (EPI == 0) {
          val += b_in[n];
          int sec = n >> 11, nn = n & 2047, hh = nn >> 7;
          if (sec == 0) {
            float qs = __expf(-2.f * log_scale[hh]) * 0.088388347648318447f; // 1/(s^2*sqrt(128))
            outq[(size_t)gi * DEXP + nn] = f2bf(val * qs);
          } else if (sec == 1) {
            outk[(size_t)gi * DEXP + nn] = f2bf(val);
          } else if (sec == 2) {
            outvt[(size_t)nn * SEQ + gi] = f2bf(val);   // V stored transposed: vt[h*128+d][i]
          } else {
            outp[(size_t)gi * DEXP + nn] = f2bf(val);
          }
        } else {
          outf[(size_t)gi * N + n] = val;
        }
      }
    }
  }
}

// ---------------- y head: dot(xn_row, W_in[8192+h]) + bias -> sigmoid -> sig_y[h][i] ------
__global__ __launch_bounds__(256) void yproj(const unsigned short* __restrict__ xn,
    const unsigned short* __restrict__ winbf, const float* __restrict__ b_in,
    float* __restrict__ sig_y) {
  int i = blockIdx.x;
  int t = threadIdx.x, wv = t >> 6, l = t & 63;
  const unsigned short* xr = xn + (size_t)i * DMODEL;
  for (int h = wv; h < NHEADS; h += 4) {
    const unsigned short* wr = winbf + (size_t)(4 * DEXP + h) * DMODEL;
    float s = 0.f;
    #pragma unroll
    for (int e = 0; e < 16; ++e) {
      int idx = l + 64 * e;
      s += bf2f(xr[idx]) * bf2f(wr[idx]);
    }
    #pragma unroll
    for (int m = 1; m < 64; m <<= 1) s += __shfl_xor(s, m, 64);
    if (l == 0) {
      float yv = s + b_in[4 * DEXP + h];
      sig_y[h * SEQ + i] = 1.f / (1.f + __expf(-yv));
    }
  }
}

// ---------------- inclusive scan of sig_y per head -> pos[h][i] ----------------
__global__ __launch_bounds__(256) void scan_kernel(const float* __restrict__ sig_y,
                                                   float* __restrict__ pos) {
  int h = blockIdx.x, t = threadIdx.x;
  const float* in = sig_y + (size_t)h * SEQ;
  float v[8], s = 0.f;
  #pragma unroll
  for (int e = 0; e < 8; ++e) { v[e] = in[t * 8 + e]; s += v[e]; }
  __shared__ float sh[256];
  sh[t] = s;
  __syncthreads();
  for (int off = 1; off < 256; off <<= 1) {
    float add = (t >= off) ? sh[t - off] : 0.f;
    __syncthreads();
    sh[t] += add;
    __syncthreads();
  }
  float run = sh[t] - s;   // exclusive prefix of thread sums
  float* op = pos + (size_t)h * SEQ;
  #pragma unroll
  for (int e = 0; e < 8; ++e) { run += v[e]; op[t * 8 + e] = run; }
}

// ---------------- smear: k <- (1-s)k_t + s k_{t-1} ----------------
__global__ void smear_kernel(const unsigned short* __restrict__ projk,
    const float* __restrict__ smearf, unsigned short* __restrict__ ksm) {
  int idx = blockIdx.x * 256 + threadIdx.x;
  if (idx >= SEQ * DEXP) return;
  int i = idx >> 11, nn = idx & 2047, h = nn >> 7;
  float sf = 1.f / (1.f + __expf(-smearf[h]));
  float kc = bf2f(projk[idx]);
  float kp = (i > 0) ? bf2f(projk[idx - DEXP]) : 0.f;
  ksm[idx] = f2bf((1.f - sf) * kc + sf * kp);
}

// ---------------- flash attention: 1 wave, paired q-tiles (qt, 127-qt) ----------------
// Stream s handles 16 rows qtv[s]*16..+15. Both streams share K/V fragment loads.
__global__ __launch_bounds__(64) void attn_kernel(
    const unsigned short* __restrict__ q, const unsigned short* __restrict__ ksm,
    const unsigned short* __restrict__ vt, const unsigned short* __restrict__ projp,
    const float* __restrict__ pos, unsigned short* __restrict__ ap) {
  int bid = blockIdx.x;
  int h = bid & (NHEADS - 1);
  int p = bid >> 4;                       // 0..63
  int qtv[2] = { p, 127 - p };            // qtv[1] > qtv[0] always
  int l = threadIdx.x;
  int c16 = l & 15, g = l >> 4;

  bf16x8 qf[2][4];
  float pos_i[2][4], m_run[2][4], l_run[2][4];
  f32x4 oacc[2][8];
  f32x4 z = {0.f, 0.f, 0.f, 0.f};
  int jtmax[2];
  #pragma unroll
  for (int s = 0; s < 2; ++s) {
    const unsigned short* qb = q + (size_t)(qtv[s] * 16 + c16) * DEXP + h * DHEAD + g * 8;
    #pragma unroll
    for (int f = 0; f < 4; ++f) qf[s][f] = *reinterpret_cast<const bf16x8*>(qb + f * 32);
    #pragma unroll
    for (int r = 0; r < 4; ++r) {
      pos_i[s][r] = pos[h * SEQ + qtv[s] * 16 + g * 4 + r];
      m_run[s][r] = -1e30f; l_run[s][r] = 0.f;
    }
    #pragma unroll
    for (int nb = 0; nb < 8; ++nb) oacc[s][nb] = z;
    jtmax[s] = (qtv[s] * 16 + 15) >> 5;
  }

  __shared__ __align__(16) unsigned short P_lds[2][16 * 36]; // stride 36 shorts = 72B

  for (int jt = 0; jt <= jtmax[1]; ++jt) {
    int j0 = jt * 32;
    // shared K fragments for both 16-col halves
    bf16x8 kv0[4], kv1[4];
    {
      const unsigned short* kb0 = ksm + (size_t)(j0 + c16) * DEXP + h * DHEAD + g * 8;
      const unsigned short* kb1 = kb0 + (size_t)16 * DEXP;
      #pragma unroll
      for (int f = 0; f < 4; ++f) {
        kv0[f] = *reinterpret_cast<const bf16x8*>(kb0 + f * 32);
        kv1[f] = *reinterpret_cast<const bf16x8*>(kb1 + f * 32);
      }
    }
    float pj0 = pos[h * SEQ + j0 + c16];
    float pj1 = pos[h * SEQ + j0 + 16 + c16];

    #pragma unroll
    for (int s = 0; s < 2; ++s) {
      if (jt > jtmax[s]) continue;   // wave-uniform
      f32x4 s0 = z, s1 = z;
      #pragma unroll
      for (int f = 0; f < 4; ++f) {
        s0 = __builtin_amdgcn_mfma_f32_16x16x32_bf16(qf[s][f], kv0[f], s0, 0, 0, 0);
        s1 = __builtin_amdgcn_mfma_f32_16x16x32_bf16(qf[s][f], kv1[f], s1, 0, 0, 0);
      }
      float v0[4], v1[4], mt[4];
      #pragma unroll
      for (int r = 0; r < 4; ++r) {
        int row = qtv[s] * 16 + g * 4 + r;
        int col0 = j0 + c16, col1 = col0 + 16;
        float a0 = s0[r] - pos_i[s][r] + pj0 + (col0 > row ? -1e10f : 0.f);
        float a1 = s1[r] - pos_i[s][r] + pj1 + (col1 > row ? -1e10f : 0.f);
        v0[r] = a0; v1[r] = a1;
        mt[r] = fmaxf(a0, a1);
      }
      #pragma unroll
      for (int r = 0; r < 4; ++r)
        #pragma unroll
        for (int m = 1; m < 16; m <<= 1)
          mt[r] = fmaxf(mt[r], __shfl_xor(mt[r], m, 64));
      float alpha[4], ps[4];
      #pragma unroll
      for (int r = 0; r < 4; ++r) {
        float mn = fmaxf(m_run[s][r], mt[r]);
        alpha[r] = __expf(m_run[s][r] - mn);
        m_run[s][r] = mn;
        float p0 = __expf(v0[r] - mn);
        float p1 = __expf(v1[r] - mn);
        P_lds[s][(g * 4 + r) * 36 + c16]      = f2bf(p0);
        P_lds[s][(g * 4 + r) * 36 + 16 + c16] = f2bf(p1);
        ps[r] = p0 + p1;
      }
      #pragma unroll
      for (int r = 0; r < 4; ++r) {
        #pragma unroll
        for (int m = 1; m < 16; m <<= 1) ps[r] += __shfl_xor(ps[r], m, 64);
        l_run[s][r] = l_run[s][r] * alpha[r] + ps[r];
      }
      #pragma unroll
      for (int nb = 0; nb < 8; ++nb)
        #pragma unroll
        for (int r = 0; r < 4; ++r) oacc[s][nb][r] *= alpha[r];
    }
    __syncthreads();
    // P as A-fragment per stream
    union { unsigned long long u[2]; bf16x8 v; } pa[2];
    #pragma unroll
    for (int s = 0; s < 2; ++s) {
      if (jt > jtmax[s]) continue;
      const unsigned long long* pl =
          reinterpret_cast<const unsigned long long*>(&P_lds[s][c16 * 36 + g * 8]);
      pa[s].u[0] = pl[0]; pa[s].u[1] = pl[1];
    }
    // shared V fragments
    const unsigned short* vb0 = vt + (size_t)(h * DHEAD + c16) * SEQ + j0 + g * 8;
    #pragma unroll
    for (int nb = 0; nb < 8; ++nb) {
      bf16x8 vf = *reinterpret_cast<const bf16x8*>(vb0 + (size_t)nb * 16 * SEQ);
      if (jt <= jtmax[0])
        oacc[0][nb] = __builtin_amdgcn_mfma_f32_16x16x32_bf16(pa[0].v, vf, oacc[0][nb], 0, 0, 0);
      oacc[1][nb] = __builtin_amdgcn_mfma_f32_16x16x32_bf16(pa[1].v, vf, oacc[1][nb], 0, 0, 0);
    }
    __syncthreads();
  }
  // epilogue: o/l, gate with silu(p), store bf16 -- both streams
  #pragma unroll
  for (int s = 0; s < 2; ++s) {
    #pragma unroll
    for (int nb = 0; nb < 8; ++nb) {
      #pragma unroll
      for (int r = 0; r < 4; ++r) {
        int row = qtv[s] * 16 + g * 4 + r;
        int nn = h * DHEAD + nb * 16 + c16;
        float o = oacc[s][nb][r] / l_run[s][r];
        float pv = bf2f(projp[(size_t)row * DEXP + nn]);
        float si = pv / (1.f + __expf(-pv));
        ap[(size_t)row * DEXP + nn] = f2bf(si * o);
      }
    }
  }
}

extern "C" void kernel_launch(void* const* d_in, const int* in_sizes, int n_in,
                              void* d_out, int out_size, void* d_ws, size_t ws_size,
                              hipStream_t stream) {
  const float* x         = (const float*)d_in[0];
  const float* W_in      = (const float*)d_in[1];
  const float* b_in      = (const float*)d_in[2];
  const float* in_ln_w   = (const float*)d_in[3];
  const float* in_ln_b   = (const float*)d_in[4];
  const float* W_out     = (const float*)d_in[5];
  const float* out_ln_w  = (const float*)d_in[6];
  const float* out_ln_b  = (const float*)d_in[7];
  const float* smearf    = (const float*)d_in[8];
  const float* log_scale = (const float*)d_in[9];
  float* out = (float*)d_out;

  char* ws = (char*)d_ws;
  size_t off = 0;
  auto alloc = [&](size_t bytes) -> void* {
    void* p = ws + off;
    off += (bytes + 255) & ~(size_t)255;
    return p;
  };
  unsigned short* xn     = (unsigned short*)alloc((size_t)SEQ * DMODEL * 2);
  unsigned short* winbf  = (unsigned short*)alloc((size_t)(4 * DEXP + NHEADS) * DMODEL * 2);
  unsigned short* woutbf = (unsigned short*)alloc((size_t)DMODEL * DEXP * 2);
  unsigned short* projq  = (unsigned short*)alloc((size_t)SEQ * DEXP * 2);
  unsigned short* projk  = (unsigned short*)alloc((size_t)SEQ * DEXP * 2);
  unsigned short* projp  = (unsigned short*)alloc((size_t)SEQ * DEXP * 2);
  unsigned short* vtb    = (unsigned short*)alloc((size_t)SEQ * DEXP * 2);
  unsigned short* ksm    = (unsigned short*)alloc((size_t)SEQ * DEXP * 2);
  unsigned short* apb    = (unsigned short*)alloc((size_t)SEQ * DEXP * 2);
  float* sig_y = (float*)alloc((size_t)NHEADS * SEQ * 4);
  float* posb  = (float*)alloc((size_t)NHEADS * SEQ * 4);
  float* outf  = (float*)alloc((size_t)SEQ * DMODEL * 4);

  int nwin4  = (4 * DEXP + NHEADS) * DMODEL / 4;
  int nwout4 = DMODEL * DEXP / 4;
  castbf4<<<(nwin4 + 255) / 256, 256, 0, stream>>>(W_in, winbf, nwin4);
  castbf4<<<(nwout4 + 255) / 256, 256, 0, stream>>>(W_out, woutbf, nwout4);
  ln_kernel<<<SEQ, 256, 0, stream>>>(x, in_ln_w, in_ln_b, xn, nullptr);
  gemm_lds<0><<<(SEQ / 128) * (4 * DEXP / 128), 256, 0, stream>>>(
      xn, winbf, SEQ, 4 * DEXP, DMODEL, b_in, log_scale, projq, projk, vtb, projp, nullptr);
  yproj<<<SEQ, 256, 0, stream>>>(xn, winbf, b_in, sig_y);
  scan_kernel<<<NHEADS, 256, 0, stream>>>(sig_y, posb);
  smear_kernel<<<(SEQ * DEXP + 255) / 256, 256, 0, stream>>>(projk, smearf, ksm);
  attn_kernel<<<NHEADS * 64, 64, 0, stream>>>(projq, ksm, vtb, projp, posb, apb);
  gemm_lds<1><<<(SEQ / 128) * (DMODEL / 128), 256, 0, stream>>>(
      apb, woutbf, SEQ, DMODEL, DEXP, nullptr, nullptr, nullptr, nullptr, nullptr, nullptr, outf);
  ln_kernel<<<SEQ, 256, 0, stream>>>(outf, out_ln_w, out_ln_b, nullptr, out);
}